// Round 5
// baseline (1059.064 us; speedup 1.0000x reference)
//
#include <hip/hip_runtime.h>

#define N_NODES 65536
#define G_GRID  32768
#define E_EDGES 600000
#define HD      128

typedef __attribute__((ext_vector_type(8))) short bf8;
typedef __attribute__((ext_vector_type(4))) float f32x4;

__device__ __forceinline__ short f2bf(float f){
  union { float f; unsigned u; } v; v.f = f;
  unsigned r = v.u + 0x7FFFu + ((v.u >> 16) & 1u);
  return (short)(r >> 16);
}

__device__ __forceinline__ bf8 load_pack8(const float* p, float scale){
  float4 u0 = *(const float4*)p;
  float4 u1 = *(const float4*)(p + 4);
  bf8 r;
  r[0]=f2bf(u0.x*scale); r[1]=f2bf(u0.y*scale); r[2]=f2bf(u0.z*scale); r[3]=f2bf(u0.w*scale);
  r[4]=f2bf(u1.x*scale); r[5]=f2bf(u1.y*scale); r[6]=f2bf(u1.z*scale); r[7]=f2bf(u1.w*scale);
  return r;
}

// ---------- weight prep ----------
__global__ void prep_w_k(const float* __restrict__ nmw1, const float* __restrict__ nmw2,
                         const float* __restrict__ emw2, const float* __restrict__ mmw1,
                         const float* __restrict__ mmw2, short* __restrict__ dst)
{
  int i = blockIdx.x*256 + threadIdx.x;  // < 98304
  const float* src; int local; bool k256 = false;
  if      (i < 16384){ src = nmw1; local = i; }
  else if (i < 32768){ src = nmw2; local = i - 16384; }
  else if (i < 49152){ src = emw2; local = i - 32768; }
  else if (i < 81920){ src = mmw1; local = i - 49152; k256 = true; }
  else               { src = mmw2; local = i - 81920; }
  int n, k;
  if (k256){ n = local >> 8; k = local & 255; }
  else     { n = local >> 7; k = local & 127; }
  dst[i] = f2bf(src[k*HD + n]);
}

// ---------- node MLP ----------
__global__ void node_mlp_k(const float* __restrict__ X,
                           const short* __restrict__ w1t, const float* __restrict__ b1,
                           const short* __restrict__ w2t, const float* __restrict__ b2,
                           short* __restrict__ nf)
{
  __shared__ short hid[64][136];
  const int t = threadIdx.x;
  const int wave = t >> 6, lane = t & 63, l15 = lane & 15, q = lane >> 4;
  const int rw = blockIdx.x*64 + wave*16;

  bf8 a[4];
  const float* xr = X + (size_t)(rw + l15)*HD;
  #pragma unroll
  for (int kt=0; kt<4; kt++) a[kt] = load_pack8(xr + kt*32 + q*8, 1.0f);

  #pragma unroll
  for (int ct=0; ct<8; ct++){
    f32x4 acc = {0.f,0.f,0.f,0.f};
    #pragma unroll
    for (int kt=0; kt<4; kt++){
      bf8 b = *(const bf8*)(w1t + (ct*16 + l15)*HD + kt*32 + q*8);
      acc = __builtin_amdgcn_mfma_f32_16x16x32_bf16(a[kt], b, acc, 0, 0, 0);
    }
    float bias = b1[ct*16 + l15];
    #pragma unroll
    for (int r=0;r<4;r++){
      float v = acc[r] + bias;
      v = v / (1.f + __expf(-v));
      hid[wave*16 + q*4 + r][ct*16 + l15] = f2bf(v);
    }
  }
  __syncthreads();

  bf8 a2[4];
  #pragma unroll
  for (int kt=0;kt<4;kt++) a2[kt] = *(const bf8*)&hid[wave*16 + l15][kt*32 + q*8];
  #pragma unroll
  for (int ct=0; ct<8; ct++){
    f32x4 acc = {0.f,0.f,0.f,0.f};
    #pragma unroll
    for (int kt=0;kt<4;kt++){
      bf8 b = *(const bf8*)(w2t + (ct*16 + l15)*HD + kt*32 + q*8);
      acc = __builtin_amdgcn_mfma_f32_16x16x32_bf16(a2[kt], b, acc, 0, 0, 0);
    }
    float bias = b2[ct*16 + l15];
    #pragma unroll
    for (int r=0;r<4;r++)
      nf[(size_t)(rw + q*4 + r)*HD + ct*16 + l15] = f2bf(acc[r] + bias);
  }
}

// ---------- CSR build ----------
__global__ void count_k(const int* __restrict__ eidx, int* __restrict__ counts){
  int e = blockIdx.x*256 + threadIdx.x;
  if (e < E_EDGES) atomicAdd(&counts[eidx[E_EDGES + e]], 1);
}

__global__ void scan_k(const int* __restrict__ counts, int* __restrict__ offs){
  __shared__ int part[1024];
  const int t = threadIdx.x;
  const int base = t*32;
  int loc[32];
  int s = 0;
  #pragma unroll
  for (int i=0;i<32;i++){ loc[i] = s; s += counts[base+i]; }
  part[t] = s;
  __syncthreads();
  for (int off=1; off<1024; off<<=1){
    int v = (t>=off) ? part[t-off] : 0;
    __syncthreads();
    part[t] += v;
    __syncthreads();
  }
  int pre = (t==0) ? 0 : part[t-1];
  #pragma unroll
  for (int i=0;i<32;i++) offs[base+i] = pre + loc[i];
  if (t==1023) offs[G_GRID] = pre + s;
}

// consumes counts (leaves zeros); count recomputed later as offs[g+1]-offs[g]
__global__ void scatter_k(const int* __restrict__ eidx, const int* __restrict__ offs,
                          int* __restrict__ counts, int* __restrict__ perm){
  int e = blockIdx.x*256 + threadIdx.x;
  if (e < E_EDGES){
    int g = eidx[E_EDGES + e];
    int slot = offs[g] + atomicSub(&counts[g], 1) - 1;
    perm[slot] = e;
  }
}

// ---------- fused edge+message with in-LDS segmented reduction ----------
// Edges processed in target-sorted order. Final msg tile parked in LDS (fp32,
// aliasing dead hm/efs via union), then 256 threads walk (col, 32-row window)
// emitting one atomicAdd per target-run instead of per edge (~12x fewer).
__global__ void __launch_bounds__(256, 4)
edge_msg_red_k(const int* __restrict__ perm, const int* __restrict__ eidx,
               const float* __restrict__ npos, const float* __restrict__ gpos,
               const float* __restrict__ ew1, const float* __restrict__ eb1,
               const short* __restrict__ ew2t, const float* __restrict__ eb2,
               const short* __restrict__ mw1t, const float* __restrict__ mb1,
               const short* __restrict__ mw2t, const float* __restrict__ mb2,
               const short* __restrict__ nf,
               float* __restrict__ agg)
{
  __shared__ float attr[64][8];
  __shared__ int srcs[64], tgts[64];
  union SmemU {
    struct { short hm[64][136]; short efs[64][136]; } s;  // 34816 B
    float msgf[64][132];                                  // 33792 B
  };
  __shared__ SmemU u;

  const int t = threadIdx.x;
  const int e0 = blockIdx.x*64;
  const int wave = t >> 6, lane = t & 63, l15 = lane & 15, q = lane >> 4;
  const int rl = wave*16;

  if (t < 64){
    int e = perm[e0 + t];
    int s = eidx[e];
    int g = eidx[E_EDGES + e];
    srcs[t] = s; tgts[t] = g;
    attr[t][0] = npos[s*3+0]; attr[t][1] = npos[s*3+1]; attr[t][2] = npos[s*3+2];
    attr[t][3] = gpos[g*3+0]; attr[t][4] = gpos[g*3+1]; attr[t][5] = gpos[g*3+2];
  }
  __syncthreads();

  // nf[src] A-fragment gather, issued early (overlaps edge-hidden1)
  bf8 an[4];
  {
    const short* nr = nf + (size_t)srcs[rl + l15]*HD + q*8;
    #pragma unroll
    for (int kt=0;kt<4;kt++) an[kt] = *(const bf8*)(nr + kt*32);
  }

  // stage 1: edge hidden1 (K=6, fp32 exact) -> hm (each wave covers 32 cols of all 64 rows)
  {
    int e = t & 63, nb = (t >> 6)*32;
    float a0=attr[e][0], a1=attr[e][1], a2=attr[e][2],
          a3=attr[e][3], a4=attr[e][4], a5=attr[e][5];
    #pragma unroll 8
    for (int j=0;j<32;j++){
      int n = nb + j;
      float v = eb1[n] + a0*ew1[n] + a1*ew1[HD+n] + a2*ew1[2*HD+n]
              + a3*ew1[3*HD+n] + a4*ew1[4*HD+n] + a5*ew1[5*HD+n];
      v = v / (1.f + __expf(-v));
      u.s.hm[e][n] = f2bf(v);
    }
  }
  __syncthreads();

  // stage 2: ef = hm @ em_w2t + eb2 -> efs (wave-local rows)
  bf8 a[4];
  #pragma unroll
  for (int kt=0;kt<4;kt++) a[kt] = *(const bf8*)&u.s.hm[rl + l15][kt*32 + q*8];
  #pragma unroll
  for (int ct=0; ct<8; ct++){
    f32x4 acc = {0.f,0.f,0.f,0.f};
    #pragma unroll
    for (int kt=0;kt<4;kt++){
      bf8 b = *(const bf8*)(ew2t + (ct*16 + l15)*HD + kt*32 + q*8);
      acc = __builtin_amdgcn_mfma_f32_16x16x32_bf16(a[kt], b, acc, 0,0,0);
    }
    float bias = eb2[ct*16 + l15];
    #pragma unroll
    for (int r=0;r<4;r++) u.s.efs[rl + q*4 + r][ct*16 + l15] = f2bf(acc[r] + bias);
  }

  // stage 3+4: msg hidden = silu(an@W1[:128] + efs@W1[128:] + mb1) -> hm (wave-local rows)
  bf8 ae[4];
  #pragma unroll
  for (int kt=0;kt<4;kt++)
    ae[kt] = *(const bf8*)&u.s.efs[rl + l15][kt*32 + q*8];
  #pragma unroll
  for (int ct=0; ct<8; ct++){
    f32x4 acc = {0.f,0.f,0.f,0.f};
    #pragma unroll
    for (int kt=0;kt<4;kt++){
      bf8 b = *(const bf8*)(mw1t + (ct*16 + l15)*256 + kt*32 + q*8);
      acc = __builtin_amdgcn_mfma_f32_16x16x32_bf16(an[kt], b, acc, 0,0,0);
    }
    #pragma unroll
    for (int kt=0;kt<4;kt++){
      bf8 b = *(const bf8*)(mw1t + (ct*16 + l15)*256 + 128 + kt*32 + q*8);
      acc = __builtin_amdgcn_mfma_f32_16x16x32_bf16(ae[kt], b, acc, 0,0,0);
    }
    float bias = mb1[ct*16 + l15];
    #pragma unroll
    for (int r=0;r<4;r++){
      float v = acc[r] + bias;
      v = v / (1.f + __expf(-v));
      u.s.hm[rl + q*4 + r][ct*16 + l15] = f2bf(v);
    }
  }

  // read am fragments (wave-local rows of hm), then barrier before msgf aliases hm/efs
  bf8 am[4];
  #pragma unroll
  for (int kt=0;kt<4;kt++) am[kt] = *(const bf8*)&u.s.hm[rl + l15][kt*32 + q*8];
  __syncthreads();

  // stage 5: msg = am @ mm_w2t + mb2 -> fp32 msgf tile in LDS
  #pragma unroll
  for (int ct=0; ct<8; ct++){
    f32x4 acc = {0.f,0.f,0.f,0.f};
    #pragma unroll
    for (int kt=0;kt<4;kt++){
      bf8 b = *(const bf8*)(mw2t + (ct*16 + l15)*HD + kt*32 + q*8);
      acc = __builtin_amdgcn_mfma_f32_16x16x32_bf16(am[kt], b, acc, 0,0,0);
    }
    float bias = mb2[ct*16 + l15];
    int col = ct*16 + l15;
    #pragma unroll
    for (int r=0;r<4;r++)
      u.msgf[rl + q*4 + r][col] = acc[r] + bias;
  }
  __syncthreads();

  // stage 6: segmented reduce over sorted targets; atomic only at run boundaries.
  // thread -> (col = t&127, window w = t>>7 of 32 rows). Run branch is wave-uniform.
  {
    int col = t & 127, w = t >> 7;
    int base = w*32;
    int cur = tgts[base];
    float sum = 0.f;
    for (int i=0;i<32;i++){
      int tgi = tgts[base+i];
      float v = u.msgf[base+i][col];
      if (tgi != cur){
        atomicAdd(&agg[(size_t)cur*HD + col], sum);
        cur = tgi; sum = v;
      } else sum += v;
    }
    atomicAdd(&agg[(size_t)cur*HD + col], sum);
  }
}

// ---------- update MLP, fp32; count = offs[g+1]-offs[g]; in-place over agg(=out) ----------
__global__ void update_mlp_k(const float* __restrict__ agg, const int* __restrict__ offs,
                             const float* __restrict__ w1, const float* __restrict__ b1,
                             const float* __restrict__ w2, const float* __restrict__ b2,
                             float* __restrict__ out)
{
  __shared__ float xs[32][129];
  __shared__ float hs[32][129];
  const int t = threadIdx.x;
  const int rb = blockIdx.x*32;
  {
    int e = t >> 3, c0 = (t & 7)*16;
    int g = rb + e;
    float c = (float)(offs[g+1] - offs[g]);
    float rcp = 1.0f / fmaxf(c, 1.0f);
    const float* p = agg + (size_t)g*HD + c0;
    #pragma unroll
    for (int i=0;i<16;i++) xs[e][c0+i] = p[i]*rcp;
  }
  __syncthreads();
  int e = t >> 3, n0 = (t & 7)*16;
  float acc[16];
  #pragma unroll
  for (int j=0;j<16;j++) acc[j] = b1[n0+j];
  for (int k=0;k<HD;k++){
    float x = xs[e][k];
    const float* wr = w1 + k*HD + n0;
    #pragma unroll
    for (int j=0;j<16;j++) acc[j] += x * wr[j];
  }
  #pragma unroll
  for (int j=0;j<16;j++){
    float v = acc[j];
    hs[e][n0+j] = v / (1.f + expf(-v));
  }
  __syncthreads();
  #pragma unroll
  for (int j=0;j<16;j++) acc[j] = b2[n0+j];
  for (int k=0;k<HD;k++){
    float x = hs[e][k];
    const float* wr = w2 + k*HD + n0;
    #pragma unroll
    for (int j=0;j<16;j++) acc[j] += x * wr[j];
  }
  float* op = out + (size_t)(rb + e)*HD + n0;
  #pragma unroll
  for (int j=0;j<16;j++) op[j] = acc[j];
}

extern "C" void kernel_launch(void* const* d_in, const int* in_sizes, int n_in,
                              void* d_out, int out_size, void* d_ws, size_t ws_size,
                              hipStream_t stream)
{
  const float* node_features = (const float*)d_in[0];
  const float* node_pos      = (const float*)d_in[1];
  const float* grid_pos      = (const float*)d_in[2];
  const int*   edge_index    = (const int*)d_in[3];
  const float* nm_w1 = (const float*)d_in[4];
  const float* nm_b1 = (const float*)d_in[5];
  const float* nm_w2 = (const float*)d_in[6];
  const float* nm_b2 = (const float*)d_in[7];
  const float* em_w1 = (const float*)d_in[8];
  const float* em_b1 = (const float*)d_in[9];
  const float* em_w2 = (const float*)d_in[10];
  const float* em_b2 = (const float*)d_in[11];
  const float* mm_w1 = (const float*)d_in[12];
  const float* mm_b1 = (const float*)d_in[13];
  const float* mm_w2 = (const float*)d_in[14];
  const float* mm_b2 = (const float*)d_in[15];
  const float* um_w1 = (const float*)d_in[16];
  const float* um_b1 = (const float*)d_in[17];
  const float* um_w2 = (const float*)d_in[18];
  const float* um_b2 = (const float*)d_in[19];
  float* out = (float*)d_out;

  char* ws = (char*)d_ws;
  // workspace layout (total ~18.9 MB; agg lives in d_out)
  short* nf    = (short*)ws;                       // 16 MB  bf16 [N,128]
  int*   counts= (int*)  (ws + 16777216ull);       // 128 KB
  int*   offs  = (int*)  (ws + 16908288ull);       // 128 KB + 4
  short* wts   = (short*)(ws + 17039424ull);       // 192 KB (8B-aligned)
  int*   perm  = (int*)  (ws + 17236032ull);       // 2.4 MB

  short* nmw1t = wts;
  short* nmw2t = wts + 16384;
  short* emw2t = wts + 32768;
  short* mmw1t = wts + 49152;
  short* mmw2t = wts + 81920;

  float* agg = out;  // accumulate mean-numerator directly in d_out

  (void)hipMemsetAsync(counts, 0, 131072, stream);
  (void)hipMemsetAsync(out, 0, (size_t)G_GRID*HD*4, stream);

  prep_w_k<<<384, 256, 0, stream>>>(nm_w1, nm_w2, em_w2, mm_w1, mm_w2, wts);
  node_mlp_k<<<N_NODES/64, 256, 0, stream>>>(node_features, nmw1t, nm_b1, nmw2t, nm_b2, nf);
  count_k<<<(E_EDGES+255)/256, 256, 0, stream>>>(edge_index, counts);
  scan_k<<<1, 1024, 0, stream>>>(counts, offs);
  scatter_k<<<(E_EDGES+255)/256, 256, 0, stream>>>(edge_index, offs, counts, perm);
  edge_msg_red_k<<<E_EDGES/64, 256, 0, stream>>>(perm, edge_index, node_pos, grid_pos,
      em_w1, em_b1, emw2t, em_b2, mmw1t, mm_b1, mmw2t, mm_b2, nf, agg);
  update_mlp_k<<<G_GRID/32, 256, 0, stream>>>(agg, offs, um_w1, um_b1, um_w2, um_b2, out);
}

// Round 6
// 556.716 us; speedup vs baseline: 1.9023x; 1.9023x over previous
//
#include <hip/hip_runtime.h>

#define N_NODES 65536
#define G_GRID  32768
#define E_EDGES 600000
#define HD      128

typedef __attribute__((ext_vector_type(8))) short bf8;
typedef __attribute__((ext_vector_type(4))) float f32x4;

__device__ __forceinline__ short f2bf(float f){
  union { float f; unsigned u; } v; v.f = f;
  unsigned r = v.u + 0x7FFFu + ((v.u >> 16) & 1u);
  return (short)(r >> 16);
}

__device__ __forceinline__ bf8 load_pack8(const float* p, float scale){
  float4 u0 = *(const float4*)p;
  float4 u1 = *(const float4*)(p + 4);
  bf8 r;
  r[0]=f2bf(u0.x*scale); r[1]=f2bf(u0.y*scale); r[2]=f2bf(u0.z*scale); r[3]=f2bf(u0.w*scale);
  r[4]=f2bf(u1.x*scale); r[5]=f2bf(u1.y*scale); r[6]=f2bf(u1.z*scale); r[7]=f2bf(u1.w*scale);
  return r;
}

// ---------- weight prep: transpose + bf16 ----------
// dst element ranges: nm_w1t[0,16384) K=128 | nm_w2t[16384,32768) | (unused)[32768,49152)
// mm_w1t[49152,81920) K=256 | mm_w2t[81920,98304) | um_w1t[98304,114688) | um_w2t[114688,131072)
__global__ void prep_w_k(const float* __restrict__ nmw1, const float* __restrict__ nmw2,
                         const float* __restrict__ emw2, const float* __restrict__ mmw1,
                         const float* __restrict__ mmw2, const float* __restrict__ umw1,
                         const float* __restrict__ umw2, short* __restrict__ dst)
{
  int i = blockIdx.x*256 + threadIdx.x;  // < 131072
  const float* src; int local; bool k256 = false;
  if      (i < 16384){ src = nmw1; local = i; }
  else if (i < 32768){ src = nmw2; local = i - 16384; }
  else if (i < 49152){ src = emw2; local = i - 32768; }
  else if (i < 81920){ src = mmw1; local = i - 49152; k256 = true; }
  else if (i < 98304){ src = mmw2; local = i - 81920; }
  else if (i < 114688){ src = umw1; local = i - 98304; }
  else               { src = umw2; local = i - 114688; }
  int n, k;
  if (k256){ n = local >> 8; k = local & 255; }
  else     { n = local >> 7; k = local & 127; }
  dst[i] = f2bf(src[k*HD + n]);
}

// ---------- fold prep: W_combo = em_w2 @ mm_w1[128:], b_combo = eb2 @ mm_w1[128:] + mb1,
// ew1c[n][8] = {em_w1[0..5][n], eb1[n], 0} ----------
__global__ void prep_combo_k(const float* __restrict__ emw1, const float* __restrict__ eb1,
                             const float* __restrict__ emw2, const float* __restrict__ eb2,
                             const float* __restrict__ mmw1, const float* __restrict__ mb1,
                             short* __restrict__ wcombot, float* __restrict__ bcombo,
                             float* __restrict__ ew1c)
{
  int gid = blockIdx.x*256 + threadIdx.x;
  if (gid < 16384){
    int n = gid >> 7, k = gid & 127;
    float acc = 0.f;
    for (int j=0;j<HD;j++) acc += emw2[k*HD + j] * mmw1[(HD + j)*HD + n];
    wcombot[n*HD + k] = f2bf(acc);
  } else if (gid < 16512){
    int n = gid - 16384;
    float acc = mb1[n];
    for (int j=0;j<HD;j++) acc += eb2[j] * mmw1[(HD + j)*HD + n];
    bcombo[n] = acc;
  } else if (gid < 16640){
    int n = gid - 16512;
    #pragma unroll
    for (int k=0;k<6;k++) ew1c[n*8 + k] = emw1[k*HD + n];
    ew1c[n*8 + 6] = eb1[n];
    ew1c[n*8 + 7] = 0.f;
  }
}

// ---------- node MLP (MFMA, 64 rows/block) ----------
__global__ void node_mlp_k(const float* __restrict__ X,
                           const short* __restrict__ w1t, const float* __restrict__ b1,
                           const short* __restrict__ w2t, const float* __restrict__ b2,
                           short* __restrict__ nf)
{
  __shared__ short hid[64][136];
  const int t = threadIdx.x;
  const int wave = t >> 6, lane = t & 63, l15 = lane & 15, q = lane >> 4;
  const int rw = blockIdx.x*64 + wave*16;

  bf8 a[4];
  const float* xr = X + (size_t)(rw + l15)*HD;
  #pragma unroll
  for (int kt=0; kt<4; kt++) a[kt] = load_pack8(xr + kt*32 + q*8, 1.0f);

  #pragma unroll
  for (int ct=0; ct<8; ct++){
    f32x4 acc = {0.f,0.f,0.f,0.f};
    #pragma unroll
    for (int kt=0; kt<4; kt++){
      bf8 b = *(const bf8*)(w1t + (ct*16 + l15)*HD + kt*32 + q*8);
      acc = __builtin_amdgcn_mfma_f32_16x16x32_bf16(a[kt], b, acc, 0, 0, 0);
    }
    float bias = b1[ct*16 + l15];
    #pragma unroll
    for (int r=0;r<4;r++){
      float v = acc[r] + bias;
      v = v / (1.f + __expf(-v));
      hid[wave*16 + q*4 + r][ct*16 + l15] = f2bf(v);
    }
  }
  __syncthreads();

  bf8 a2[4];
  #pragma unroll
  for (int kt=0;kt<4;kt++) a2[kt] = *(const bf8*)&hid[wave*16 + l15][kt*32 + q*8];
  #pragma unroll
  for (int ct=0; ct<8; ct++){
    f32x4 acc = {0.f,0.f,0.f,0.f};
    #pragma unroll
    for (int kt=0;kt<4;kt++){
      bf8 b = *(const bf8*)(w2t + (ct*16 + l15)*HD + kt*32 + q*8);
      acc = __builtin_amdgcn_mfma_f32_16x16x32_bf16(a2[kt], b, acc, 0, 0, 0);
    }
    float bias = b2[ct*16 + l15];
    #pragma unroll
    for (int r=0;r<4;r++)
      nf[(size_t)(rw + q*4 + r)*HD + ct*16 + l15] = f2bf(acc[r] + bias);
  }
}

// ---------- CSR build ----------
__global__ void count_k(const int* __restrict__ eidx, int* __restrict__ counts){
  int e = blockIdx.x*256 + threadIdx.x;
  if (e < E_EDGES) atomicAdd(&counts[eidx[E_EDGES + e]], 1);
}

__global__ void scan_k(const int* __restrict__ counts, int* __restrict__ offs){
  __shared__ int part[1024];
  const int t = threadIdx.x;
  const int base = t*32;
  int loc[32];
  int s = 0;
  #pragma unroll
  for (int i=0;i<32;i++){ loc[i] = s; s += counts[base+i]; }
  part[t] = s;
  __syncthreads();
  for (int off=1; off<1024; off<<=1){
    int v = (t>=off) ? part[t-off] : 0;
    __syncthreads();
    part[t] += v;
    __syncthreads();
  }
  int pre = (t==0) ? 0 : part[t-1];
  #pragma unroll
  for (int i=0;i<32;i++) offs[base+i] = pre + loc[i];
  if (t==1023) offs[G_GRID] = pre + s;
}

// consumes counts (leaves zeros); counts recomputed later as offs[g+1]-offs[g].
// writes target-sorted src/tgt arrays (coalesced consumption downstream).
__global__ void scatter_k(const int* __restrict__ eidx, const int* __restrict__ offs,
                          int* __restrict__ counts,
                          int* __restrict__ srcs_s, int* __restrict__ tgts_s){
  int e = blockIdx.x*256 + threadIdx.x;
  if (e < E_EDGES){
    int g = eidx[E_EDGES + e];
    int slot = offs[g] + atomicSub(&counts[g], 1) - 1;
    srcs_s[slot] = eidx[e];
    tgts_s[slot] = g;
  }
}

// ---------- fused edge+message, folded + 128 edges/block ----------
// msg_hidden = silu(nf[src]@mw1a + h@W_combo + b_combo), h = silu(pos6@ew1+eb1)
// msg = msg_hidden @ mw2t + mb2 -> in-LDS segmented reduce -> few atomics.
__global__ void __launch_bounds__(256, 3)
edge_msg2_k(const int* __restrict__ srcs_s, const int* __restrict__ tgts_s,
            const float* __restrict__ npos, const float* __restrict__ gpos,
            const float* __restrict__ ew1c_g, const float* __restrict__ bcombo,
            const short* __restrict__ mw1t, const short* __restrict__ wcombot,
            const short* __restrict__ mw2t, const float* __restrict__ mb2,
            const short* __restrict__ nf, float* __restrict__ agg)
{
  __shared__ float attr[128][9];
  __shared__ int tgtl[128];
  __shared__ float ew1l[128][8];
  union SmemU {
    short hm[128][136];   // 34816 B: edge hidden1 -> msg hidden (both tiles)
    float msgf[64][132];  // 33792 B: fp32 msg tile (one 64-tile at a time)
  };
  __shared__ SmemU u;

  const int t = threadIdx.x;
  const int e0 = blockIdx.x*128;
  const int wave = t >> 6, lane = t & 63, l15 = lane & 15, q = lane >> 4;
  const int rl = wave*16;
  const bool v1 = (e0 + 64 < E_EDGES);   // tile1 valid?

  // per-lane src ids for MFMA A-row gathers (coalesced dword loads)
  int i0 = e0 + rl + l15;
  int i1 = e0 + 64 + rl + l15; if (i1 >= E_EDGES) i1 = E_EDGES - 1;
  int s0 = srcs_s[i0];
  int s1 = srcs_s[i1];

  // issue nf gathers EARLY (overlap everything below)
  bf8 an0[4], an1[4];
  {
    const short* n0p = nf + (size_t)s0*HD + q*8;
    const short* n1p = nf + (size_t)s1*HD + q*8;
    #pragma unroll
    for (int kt=0;kt<4;kt++){ an0[kt] = *(const bf8*)(n0p + kt*32); an1[kt] = *(const bf8*)(n1p + kt*32); }
  }

  if (t < 128){
    int idx = e0 + t; if (idx >= E_EDGES) idx = E_EDGES - 1;
    int s = srcs_s[idx], g = tgts_s[idx];
    tgtl[t] = g;
    attr[t][0] = npos[s*3+0]; attr[t][1] = npos[s*3+1]; attr[t][2] = npos[s*3+2];
    attr[t][3] = gpos[g*3+0]; attr[t][4] = gpos[g*3+1]; attr[t][5] = gpos[g*3+2];
  } else {
    int r = t - 128;  // 0..127: stage ew1c row
    *(f32x4*)&ew1l[r][0] = *(const f32x4*)&ew1c_g[r*8];
    *(f32x4*)&ew1l[r][4] = *(const f32x4*)&ew1c_g[r*8 + 4];
  }
  __syncthreads();

  // stage 1: edge hidden1 (K=6, fp32 exact) -> hm. thread: edge t&127, 64 cols.
  {
    int e = t & 127, nb = (t >> 7)*64;
    float a0=attr[e][0], a1=attr[e][1], a2=attr[e][2],
          a3=attr[e][3], a4=attr[e][4], a5=attr[e][5];
    #pragma unroll
    for (int jg=0; jg<8; jg++){
      bf8 pk;
      #pragma unroll
      for (int j=0;j<8;j++){
        int n = nb + jg*8 + j;
        f32x4 w0 = *(const f32x4*)&ew1l[n][0];
        f32x4 w1 = *(const f32x4*)&ew1l[n][4];
        float v = w1[2] + a0*w0[0] + a1*w0[1] + a2*w0[2] + a3*w0[3] + a4*w1[0] + a5*w1[1];
        v = v / (1.f + __expf(-v));
        pk[j] = f2bf(v);
      }
      *(bf8*)&u.hm[e][nb + jg*8] = pk;   // b128 write
    }
  }
  __syncthreads();

  // A-fragments of hidden1 for both tiles
  bf8 ah0[4], ah1[4];
  #pragma unroll
  for (int kt=0;kt<4;kt++){
    ah0[kt] = *(const bf8*)&u.hm[rl + l15][kt*32 + q*8];
    ah1[kt] = *(const bf8*)&u.hm[64 + rl + l15][kt*32 + q*8];
  }

  // stage 3': msg hidden = silu(an@mw1a + ah@W_combo + b_combo) -> hm (wave-local rows)
  #pragma unroll
  for (int ct=0; ct<8; ct++){
    bf8 bw1[4], bwc[4];
    #pragma unroll
    for (int kt=0;kt<4;kt++){
      bw1[kt] = *(const bf8*)(mw1t + (ct*16 + l15)*256 + kt*32 + q*8);   // mw1a half
      bwc[kt] = *(const bf8*)(wcombot + (ct*16 + l15)*HD + kt*32 + q*8);
    }
    f32x4 acc0 = {0.f,0.f,0.f,0.f}, acc1 = {0.f,0.f,0.f,0.f};
    #pragma unroll
    for (int kt=0;kt<4;kt++){
      acc0 = __builtin_amdgcn_mfma_f32_16x16x32_bf16(an0[kt], bw1[kt], acc0, 0,0,0);
      acc1 = __builtin_amdgcn_mfma_f32_16x16x32_bf16(an1[kt], bw1[kt], acc1, 0,0,0);
    }
    #pragma unroll
    for (int kt=0;kt<4;kt++){
      acc0 = __builtin_amdgcn_mfma_f32_16x16x32_bf16(ah0[kt], bwc[kt], acc0, 0,0,0);
      acc1 = __builtin_amdgcn_mfma_f32_16x16x32_bf16(ah1[kt], bwc[kt], acc1, 0,0,0);
    }
    float bias = bcombo[ct*16 + l15];
    int col = ct*16 + l15;
    #pragma unroll
    for (int r=0;r<4;r++){
      float v0 = acc0[r] + bias;
      v0 = v0 / (1.f + __expf(-v0));
      u.hm[rl + q*4 + r][col] = f2bf(v0);
      float v1f = acc1[r] + bias;
      v1f = v1f / (1.f + __expf(-v1f));
      u.hm[64 + rl + q*4 + r][col] = f2bf(v1f);
    }
  }

  // read msg-hidden A-fragments for both tiles (wave-local rows), then alias hm->msgf
  bf8 am0[4], am1[4];
  #pragma unroll
  for (int kt=0;kt<4;kt++){
    am0[kt] = *(const bf8*)&u.hm[rl + l15][kt*32 + q*8];
    am1[kt] = *(const bf8*)&u.hm[64 + rl + l15][kt*32 + q*8];
  }
  __syncthreads();

  // ---- tile0: msg GEMM -> msgf -> segmented reduce ----
  #pragma unroll
  for (int ct=0; ct<8; ct++){
    f32x4 acc = {0.f,0.f,0.f,0.f};
    #pragma unroll
    for (int kt=0;kt<4;kt++){
      bf8 b = *(const bf8*)(mw2t + (ct*16 + l15)*HD + kt*32 + q*8);
      acc = __builtin_amdgcn_mfma_f32_16x16x32_bf16(am0[kt], b, acc, 0,0,0);
    }
    float bias = mb2[ct*16 + l15];
    int col = ct*16 + l15;
    #pragma unroll
    for (int r=0;r<4;r++) u.msgf[rl + q*4 + r][col] = acc[r] + bias;
  }
  __syncthreads();
  {
    int col = t & 127, w = t >> 7;
    int base = w*32;
    int cur = tgtl[base];
    float sum = 0.f;
    for (int i=0;i<32;i++){
      int tg = tgtl[base+i];
      float v = u.msgf[base+i][col];
      if (tg != cur){ atomicAdd(&agg[(size_t)cur*HD + col], sum); cur = tg; sum = v; }
      else sum += v;
    }
    atomicAdd(&agg[(size_t)cur*HD + col], sum);
  }

  // ---- tile1 (guarded, block-uniform) ----
  if (v1){
    __syncthreads();
    #pragma unroll
    for (int ct=0; ct<8; ct++){
      f32x4 acc = {0.f,0.f,0.f,0.f};
      #pragma unroll
      for (int kt=0;kt<4;kt++){
        bf8 b = *(const bf8*)(mw2t + (ct*16 + l15)*HD + kt*32 + q*8);
        acc = __builtin_amdgcn_mfma_f32_16x16x32_bf16(am1[kt], b, acc, 0,0,0);
      }
      float bias = mb2[ct*16 + l15];
      int col = ct*16 + l15;
      #pragma unroll
      for (int r=0;r<4;r++) u.msgf[rl + q*4 + r][col] = acc[r] + bias;
    }
    __syncthreads();
    {
      int col = t & 127, w = t >> 7;
      int base = w*32;
      int cur = tgtl[64 + base];
      float sum = 0.f;
      for (int i=0;i<32;i++){
        int tg = tgtl[64 + base+i];
        float v = u.msgf[base+i][col];
        if (tg != cur){ atomicAdd(&agg[(size_t)cur*HD + col], sum); cur = tg; sum = v; }
        else sum += v;
      }
      atomicAdd(&agg[(size_t)cur*HD + col], sum);
    }
  }
}

// ---------- update MLP (MFMA bf16, fp32 accum), in-place over agg(=d_out) ----------
// Each wave reads only rows [rw+0,16) it later writes -> race-free in-place.
__global__ void update_mlp2_k(const float* __restrict__ agg, const int* __restrict__ offs,
                              const short* __restrict__ w1t, const float* __restrict__ b1,
                              const short* __restrict__ w2t, const float* __restrict__ b2,
                              float* __restrict__ out)
{
  __shared__ short hid[64][136];
  const int t = threadIdx.x;
  const int wave = t >> 6, lane = t & 63, l15 = lane & 15, q = lane >> 4;
  const int rw = blockIdx.x*64 + wave*16;

  int row = rw + l15;
  float c = (float)(offs[row+1] - offs[row]);
  float rcp = 1.0f / fmaxf(c, 1.0f);
  bf8 a[4];
  const float* ar = agg + (size_t)row*HD;
  #pragma unroll
  for (int kt=0; kt<4; kt++) a[kt] = load_pack8(ar + kt*32 + q*8, rcp);

  #pragma unroll
  for (int ct=0; ct<8; ct++){
    f32x4 acc = {0.f,0.f,0.f,0.f};
    #pragma unroll
    for (int kt=0; kt<4; kt++){
      bf8 b = *(const bf8*)(w1t + (ct*16 + l15)*HD + kt*32 + q*8);
      acc = __builtin_amdgcn_mfma_f32_16x16x32_bf16(a[kt], b, acc, 0, 0, 0);
    }
    float bias = b1[ct*16 + l15];
    #pragma unroll
    for (int r=0;r<4;r++){
      float v = acc[r] + bias;
      v = v / (1.f + __expf(-v));
      hid[wave*16 + q*4 + r][ct*16 + l15] = f2bf(v);
    }
  }
  __syncthreads();

  bf8 a2[4];
  #pragma unroll
  for (int kt=0;kt<4;kt++) a2[kt] = *(const bf8*)&hid[wave*16 + l15][kt*32 + q*8];
  #pragma unroll
  for (int ct=0; ct<8; ct++){
    f32x4 acc = {0.f,0.f,0.f,0.f};
    #pragma unroll
    for (int kt=0;kt<4;kt++){
      bf8 b = *(const bf8*)(w2t + (ct*16 + l15)*HD + kt*32 + q*8);
      acc = __builtin_amdgcn_mfma_f32_16x16x32_bf16(a2[kt], b, acc, 0, 0, 0);
    }
    float bias = b2[ct*16 + l15];
    #pragma unroll
    for (int r=0;r<4;r++)
      out[(size_t)(rw + q*4 + r)*HD + ct*16 + l15] = acc[r] + bias;
  }
}

extern "C" void kernel_launch(void* const* d_in, const int* in_sizes, int n_in,
                              void* d_out, int out_size, void* d_ws, size_t ws_size,
                              hipStream_t stream)
{
  const float* node_features = (const float*)d_in[0];
  const float* node_pos      = (const float*)d_in[1];
  const float* grid_pos      = (const float*)d_in[2];
  const int*   edge_index    = (const int*)d_in[3];
  const float* nm_w1 = (const float*)d_in[4];
  const float* nm_b1 = (const float*)d_in[5];
  const float* nm_w2 = (const float*)d_in[6];
  const float* nm_b2 = (const float*)d_in[7];
  const float* em_w1 = (const float*)d_in[8];
  const float* em_b1 = (const float*)d_in[9];
  const float* em_w2 = (const float*)d_in[10];
  const float* em_b2 = (const float*)d_in[11];
  const float* mm_w1 = (const float*)d_in[12];
  const float* mm_b1 = (const float*)d_in[13];
  const float* mm_w2 = (const float*)d_in[14];
  const float* mm_b2 = (const float*)d_in[15];
  const float* um_w1 = (const float*)d_in[16];
  const float* um_b1 = (const float*)d_in[17];
  const float* um_w2 = (const float*)d_in[18];
  const float* um_b2 = (const float*)d_in[19];
  float* out = (float*)d_out;

  char* ws = (char*)d_ws;
  // workspace layout (~22.1 MB)
  short* nf     = (short*)ws;                        // 16 MB  bf16 [N,128]
  int*   counts = (int*)  (ws + 16777216ull);        // 128 KB
  int*   offs   = (int*)  (ws + 16908288ull);        // 128 KB + 64
  short* wts    = (short*)(ws + 17039424ull);        // 256 KB bf16 transposed
  short* wcombot= (short*)(ws + 17301568ull);        // 32 KB
  float* bcombo = (float*)(ws + 17334336ull);        // 512 B
  float* ew1c   = (float*)(ws + 17334848ull);        // 4 KB
  int*   srcs_s = (int*)  (ws + 17338944ull);        // 2.4 MB
  int*   tgts_s = (int*)  (ws + 19738944ull);        // 2.4 MB

  short* nmw1t = wts;
  short* nmw2t = wts + 16384;
  short* mmw1t = wts + 49152;   // [n][256]
  short* mmw2t = wts + 81920;
  short* umw1t = wts + 98304;
  short* umw2t = wts + 114688;

  float* agg = out;  // accumulate mean-numerator directly in d_out

  (void)hipMemsetAsync(counts, 0, 131072, stream);
  (void)hipMemsetAsync(out, 0, (size_t)G_GRID*HD*4, stream);

  prep_w_k<<<512, 256, 0, stream>>>(nm_w1, nm_w2, em_w2, mm_w1, mm_w2, um_w1, um_w2, wts);
  prep_combo_k<<<65, 256, 0, stream>>>(em_w1, em_b1, em_w2, em_b2, mm_w1, mm_b1,
                                       wcombot, bcombo, ew1c);
  node_mlp_k<<<N_NODES/64, 256, 0, stream>>>(node_features, nmw1t, nm_b1, nmw2t, nm_b2, nf);
  count_k<<<(E_EDGES+255)/256, 256, 0, stream>>>(edge_index, counts);
  scan_k<<<1, 1024, 0, stream>>>(counts, offs);
  scatter_k<<<(E_EDGES+255)/256, 256, 0, stream>>>(edge_index, offs, counts, srcs_s, tgts_s);
  edge_msg2_k<<<(E_EDGES + 127)/128, 256, 0, stream>>>(srcs_s, tgts_s, node_pos, grid_pos,
      ew1c, bcombo, mmw1t, wcombot, mmw2t, mm_b2, nf, agg);
  update_mlp2_k<<<G_GRID/64, 256, 0, stream>>>(agg, offs, umw1t, um_b1, umw2t, um_b2, out);
}